// Round 3
// baseline (297.227 us; speedup 1.0000x reference)
//
#include <hip/hip_runtime.h>
#include <stdint.h>
#include <stddef.h>

typedef _Float16 f16;
typedef __attribute__((ext_vector_type(8))) _Float16 f16x8;
typedef __attribute__((ext_vector_type(4))) _Float16 f16x4;
typedef __attribute__((ext_vector_type(4))) float f32x4;

#define DINL __device__ __forceinline__

// Async global->LDS 16B copy (HW-validated in this session).
DINL void async_cp16(void* lds, const void* gmem) {
    __builtin_amdgcn_global_load_lds(
        (const __attribute__((address_space(1))) void*)(uintptr_t)gmem,
        (__attribute__((address_space(3))) void*)(uint32_t)(uintptr_t)lds,
        16, 0, 0);
}

// ---------------------------------------------------------------- fused cast f32->f16
// Ranges (in float4 units): x 2097152 | w_qkv 786432 (first 262144 scaled by qs) | w_out 262144
__global__ void cast_fused(const float* __restrict__ x, f16* __restrict__ xh,
                           const float* __restrict__ wq, f16* __restrict__ wqh,
                           const float* __restrict__ wo, f16* __restrict__ woh,
                           float qs) {
    int stride = gridDim.x * blockDim.x;
    for (int i = blockIdx.x * blockDim.x + threadIdx.x; i < 3145728; i += stride) {
        const float4* src; f16x4* dst; float s = 1.f;
        if (i < 2097152)      { src = (const float4*)x  + i;            dst = (f16x4*)xh  + i; }
        else if (i < 2883584) { int j = i - 2097152; src = (const float4*)wq + j; dst = (f16x4*)wqh + j;
                                if (j < 262144) s = qs; }
        else                  { int j = i - 2883584; src = (const float4*)wo + j; dst = (f16x4*)woh + j; }
        float4 v = *src;
        f16x4 h = { (f16)(v.x * s), (f16)(v.y * s), (f16)(v.z * s), (f16)(v.w * s) };
        *dst = h;
    }
}

// ---------------------------------------------------------------- MFMA GEMM: C = A * B^T (+bias)
template <typename TC, bool HAS_BIAS>
__global__ __launch_bounds__(256) void gemm_bt(
    const f16* __restrict__ A, const f16* __restrict__ B,
    TC* __restrict__ C, const float* __restrict__ bias,
    int M, int N, int K)
{
    constexpr int BK = 64;
    __shared__ __align__(16) f16 As[128 * BK];
    __shared__ __align__(16) f16 Bs[128 * BK];

    const int tid  = threadIdx.x;
    const int lane = tid & 63;
    const int wave = tid >> 6;
    const int bm = blockIdx.y * 128;
    const int bn = blockIdx.x * 128;
    const int wr = (wave >> 1) * 64;
    const int wc = (wave & 1) * 64;

    f32x4 acc[4][4] = {};

    for (int k0 = 0; k0 < K; k0 += BK) {
#pragma unroll
        for (int it = 0; it < 4; ++it) {
            int s = tid + it * 256, row = s >> 3, cc = (s & 7) ^ (row & 7);
            async_cp16(&As[(size_t)s * 8], &A[(size_t)(bm + row) * K + k0 + cc * 8]);
        }
#pragma unroll
        for (int it = 0; it < 4; ++it) {
            int s = tid + it * 256, row = s >> 3, cc = (s & 7) ^ (row & 7);
            async_cp16(&Bs[(size_t)s * 8], &B[(size_t)(bn + row) * K + k0 + cc * 8]);
        }
        __syncthreads();

#pragma unroll
        for (int ks = 0; ks < BK; ks += 32) {
            const int rlo = lane & 15;
            const int c = (ks >> 3) + (lane >> 4);
            f16x8 af[4], bf[4];
#pragma unroll
            for (int m = 0; m < 4; ++m) {
                int r = wr + m * 16 + rlo;
                af[m] = *(const f16x8*)&As[(r * 8 + (c ^ (r & 7))) * 8];
            }
#pragma unroll
            for (int n = 0; n < 4; ++n) {
                int r = wc + n * 16 + rlo;
                bf[n] = *(const f16x8*)&Bs[(r * 8 + (c ^ (r & 7))) * 8];
            }
#pragma unroll
            for (int m = 0; m < 4; ++m)
#pragma unroll
                for (int n = 0; n < 4; ++n)
                    acc[m][n] = __builtin_amdgcn_mfma_f32_16x16x32_f16(af[m], bf[n], acc[m][n], 0, 0, 0);
        }
        __syncthreads();
    }

#pragma unroll
    for (int n = 0; n < 4; ++n) {
        const int gc = bn + wc + n * 16 + (lane & 15);
        float bv = 0.f;
        if constexpr (HAS_BIAS) bv = bias[gc];
#pragma unroll
        for (int m = 0; m < 4; ++m) {
            const int gr0 = bm + wr + m * 16 + ((lane >> 4) << 2);
#pragma unroll
            for (int r = 0; r < 4; ++r) {
                float v = acc[m][n][r] + bv;
                if constexpr (sizeof(TC) == 4) C[(size_t)(gr0 + r) * N + gc] = v;
                else                           C[(size_t)(gr0 + r) * N + gc] = (f16)v;
            }
        }
    }
}

// ---------------------------------------------------------------- V transpose: QKV -> Vt[bh][d][seq]
__global__ __launch_bounds__(256) void transpose_v(const f16* __restrict__ qkv, f16* __restrict__ vt) {
    __shared__ float T[64][65];
    const int bid = blockIdx.x, bh = bid >> 5, st = bid & 31;
    const int b = bh >> 4, h = bh & 15, s0 = st * 64;
    const int tid = threadIdx.x;
    const int rs = tid >> 2, c0 = (tid & 3) * 16;
    const f16* src = &qkv[(size_t)(b * 2048 + s0 + rs) * 3072 + 2048 + h * 64 + c0];
    f16x8 v0 = ((const f16x8*)src)[0], v1 = ((const f16x8*)src)[1];
#pragma unroll
    for (int e = 0; e < 8; ++e) { T[rs][c0 + e] = (float)v0[e]; T[rs][c0 + 8 + e] = (float)v1[e]; }
    __syncthreads();
    const int rd = tid >> 2, k0 = (tid & 3) * 16;
    f16x8 w0, w1;
#pragma unroll
    for (int e = 0; e < 8; ++e) { w0[e] = (f16)T[k0 + e][rd]; w1[e] = (f16)T[k0 + 8 + e][rd]; }
    f16* dst = &vt[(size_t)(bh * 64 + rd) * 2048 + s0 + k0];
    ((f16x8*)dst)[0] = w0; ((f16x8*)dst)[1] = w1;
}

// ---------------------------------------------------------------- MFMA flash attention v6
// v5's zero-movement P (phi key-permuted K staging makes QK^T accumulators the
// PV A-fragments) + QB=2: each wave owns TWO 16-row q-groups (32 q-rows/wave,
// 128/block). All waves read identical K/V fragments from LDS, so each
// kf/vb ds_read_b128 now feeds 2 MFMAs -> LDS traffic, staging VALU, and
// barrier count per q-row are halved. Grid: 64 bh x 16 qb = 1024 blocks =
// exactly 4/CU (32 KB LDS, <=128 VGPR via launch_bounds).
DINL int phi_row(int r) {
    return (r & 32) | ((r & 12) << 1) | ((r & 16) >> 2) | (r & 3);
}

__global__ __launch_bounds__(256, 4) void attn_mfma(
    const f16* __restrict__ qkv, const f16* __restrict__ vt, f16* __restrict__ out)
{
    constexpr int TD = 3072;
    constexpr int KSTR = 64 * TD;                  // K global advance per tile (f16 elems)
    __shared__ __align__(16) f16 Ks[2][64 * 64];
    __shared__ __align__(16) f16 Vs[2][64 * 64];   // V^T: row=dim, col=key

    const int tid = threadIdx.x, lane = tid & 63, wave = tid >> 6;
    const int bh = blockIdx.x, b = bh >> 4, h = bh & 15;
    const int q0 = blockIdx.y * 128;
    const size_t base = (size_t)b * 2048 * TD + h * 64;
    const int lo = lane & 15, hi = lane >> 4;

    // Q fragments straight from global (B-operand: row = q, k-chunk = hi*8 + 32*ks)
    f16x8 qf[2][2];
#pragma unroll
    for (int g = 0; g < 2; ++g) {
        const f16* qp = &qkv[base + (size_t)(q0 + wave * 32 + g * 16 + lo) * TD + hi * 8];
        qf[g][0] = *(const f16x8*)qp;
        qf[g][1] = *(const f16x8*)(qp + 32);
    }

    // ---- staging pointers (advance by constant stride per tile)
    const int s1 = tid,        r1 = s1 >> 3, c1 = (s1 & 7) ^ (r1 & 7);
    const int s2 = tid + 256,  r2 = s2 >> 3, c2 = (s2 & 7) ^ (r2 & 7);
    const f16* kg1 = &qkv[base + 1024 + (size_t)phi_row(r1) * TD + c1 * 8];
    const f16* kg2 = &qkv[base + 1024 + (size_t)phi_row(r2) * TD + c2 * 8];
    const f16* vg1 = &vt[(size_t)(bh * 64 + r1) * 2048 + c1 * 8];
    const f16* vg2 = &vt[(size_t)(bh * 64 + r2) * 2048 + c2 * 8];
    f16* kd1 = &Ks[0][s1 * 8]; f16* kd2 = &Ks[0][s2 * 8];
    f16* vd1 = &Vs[0][s1 * 8]; f16* vd2 = &Vs[0][s2 * 8];

    // prologue: stage tile 0 into buffer 0
    async_cp16(kd1, kg1); async_cp16(kd2, kg2);
    async_cp16(vd1, vg1); async_cp16(vd2, vg2);
    kg1 += KSTR; kg2 += KSTR; vg1 += 64; vg2 += 64;

    float lsum[2] = {};
    f32x4 o_[2][4] = {};

    for (int jt = 0; jt < 32; ++jt) {
        const int cur = jt & 1;
        __syncthreads();                      // drains staging -> buf[cur] ready
        if (jt + 1 < 32) {
            const int nb = (cur ^ 1) * 4096;  // f16 offset to alt buffer
            async_cp16(kd1 + nb, kg1); async_cp16(kd2 + nb, kg2);
            async_cp16(vd1 + nb, vg1); async_cp16(vd2 + nb, vg2);
            kg1 += KSTR; kg2 += KSTR; vg1 += 64; vg2 += 64;
        }

        // ---- S^T = K Q^T : sc[g][n] col = q(lo), row = LDS K row (16n + 4hi + r); log2 domain
        f32x4 sc[2][4] = {{}, {}};
#pragma unroll
        for (int ks = 0; ks < 2; ++ks) {
            const int c = ks * 4 + hi;
#pragma unroll
            for (int n = 0; n < 4; ++n) {
                int kr = n * 16 + lo;
                f16x8 kf = *(const f16x8*)&Ks[cur][(kr * 8 + (c ^ (kr & 7))) * 8];
                sc[0][n] = __builtin_amdgcn_mfma_f32_16x16x32_f16(kf, qf[0][ks], sc[0][n], 0, 0, 0);
                sc[1][n] = __builtin_amdgcn_mfma_f32_16x16x32_f16(kf, qf[1][ks], sc[1][n], 0, 0, 0);
            }
        }

        // ---- P = exp2(S^T) packed directly into PV A-fragments (phi makes layouts match)
        f16x8 pa[2][2];
#pragma unroll
        for (int g = 0; g < 2; ++g)
#pragma unroll
        for (int n = 0; n < 4; ++n) {
            float p0 = exp2f(sc[g][n][0]), p1 = exp2f(sc[g][n][1]);
            float p2 = exp2f(sc[g][n][2]), p3 = exp2f(sc[g][n][3]);
            lsum[g] += (p0 + p1) + (p2 + p3);
            const int off = (n & 1) * 4;
            const int w = n >> 1;
            pa[g][w][off]   = (f16)p0; pa[g][w][off+1] = (f16)p1;
            pa[g][w][off+2] = (f16)p2; pa[g][w][off+3] = (f16)p3;
        }

        // ---- O += P V  (A = pa (in regs), B = V^T[dim][key])
#pragma unroll
        for (int ks = 0; ks < 2; ++ks) {
            const int c = ks * 4 + hi;
#pragma unroll
            for (int n = 0; n < 4; ++n) {
                int dd = n * 16 + lo;
                f16x8 vb = *(const f16x8*)&Vs[cur][(dd * 8 + (c ^ (dd & 7))) * 8];
                o_[0][n] = __builtin_amdgcn_mfma_f32_16x16x32_f16(pa[0][ks], vb, o_[0][n], 0, 0, 0);
                o_[1][n] = __builtin_amdgcn_mfma_f32_16x16x32_f16(pa[1][ks], vb, o_[1][n], 0, 0, 0);
            }
        }
    }

    // ---- denominators: sum across the 4 hi-groups, then fetch per output row
#pragma unroll
    for (int g = 0; g < 2; ++g) {
        float ls = lsum[g];
        ls += __shfl_xor(ls, 16);
        ls += __shfl_xor(ls, 32);
#pragma unroll
        for (int r = 0; r < 4; ++r) {
            float inv = 1.f / __shfl(ls, hi * 4 + r);
            int row = q0 + wave * 32 + g * 16 + hi * 4 + r;
#pragma unroll
            for (int n = 0; n < 4; ++n) {
                int dim = h * 64 + n * 16 + lo;
                out[(size_t)(b * 2048 + row) * 1024 + dim] = (f16)(o_[g][n][r] * inv);
            }
        }
    }
}

// ---------------------------------------------------------------- launch
extern "C" void kernel_launch(void* const* d_in, const int* in_sizes, int n_in,
                              void* d_out, int out_size, void* d_ws, size_t ws_size,
                              hipStream_t stream)
{
    int ix = 0, iq = 1, iw = 2, ib = 3;
    for (int i = 0; i < n_in; ++i) {
        if      (in_sizes[i] == 8388608) ix = i;
        else if (in_sizes[i] == 3145728) iq = i;
        else if (in_sizes[i] == 1048576) iw = i;
        else if (in_sizes[i] == 1024)    ib = i;
    }
    const float* x     = (const float*)d_in[ix];
    const float* w_qkv = (const float*)d_in[iq];
    const float* w_out = (const float*)d_in[iw];
    const float* b_out = (const float*)d_in[ib];

    char* ws = (char*)d_ws;
    f16* Xh    = (f16*)(ws + 0);           // 16 MiB (AOh overlays after gemm1)
    f16* AOh   = Xh;
    f16* Wqkvh = (f16*)(ws + 16777216);    //  6 MiB
    f16* QKVh  = (f16*)(ws + 23068672);    // 48 MiB [8192][3072]
    f16* Vth   = (f16*)(ws + 73400320);    // 16 MiB [64][64][2048]
    f16* Wouth = (f16*)(ws + 90177536);    //  2 MiB (end 92,274,688 = r1-proven extent)

    // Fold softmax scale * log2(e) into W_q rows.
    const float QSCALE = 0.03125f * 1.4426950408889634f;

    cast_fused<<<3072, 256, 0, stream>>>(x, Xh, w_qkv, Wqkvh, w_out, Wouth, QSCALE);

    // QKV = X @ Wqkv^T : M=8192, N=3072, K=1024
    gemm_bt<f16, false><<<dim3(24, 64), 256, 0, stream>>>(
        Xh, Wqkvh, QKVh, nullptr, 8192, 3072, 1024);

    transpose_v<<<2048, 256, 0, stream>>>(QKVh, Vth);

    attn_mfma<<<dim3(64, 16), 256, 0, stream>>>(QKVh, Vth, AOh);

    // out = AO @ Wout^T + b : fp32 output
    gemm_bt<float, true><<<dim3(8, 64), 256, 0, stream>>>(
        AOh, Wouth, (float*)d_out, b_out, 8192, 1024, 1024);
}

// Round 6
// 290.054 us; speedup vs baseline: 1.0247x; 1.0247x over previous
//
#include <hip/hip_runtime.h>
#include <stdint.h>
#include <stddef.h>

typedef _Float16 f16;
typedef __attribute__((ext_vector_type(8))) _Float16 f16x8;
typedef __attribute__((ext_vector_type(4))) _Float16 f16x4;
typedef __attribute__((ext_vector_type(4))) float f32x4;

#define DINL __device__ __forceinline__

// Async global->LDS 16B copy. NOTE (R4/R5 root cause): the hardware writes
// LDS at wave-uniform base + lane*16 -- the per-lane LDS address is IGNORED
// beyond the base. LDS destinations must be linear in lane; any swizzle
// must be applied to the GLOBAL SOURCE address instead.
DINL void async_cp16(void* lds, const void* gmem) {
    __builtin_amdgcn_global_load_lds(
        (const __attribute__((address_space(1))) void*)(uintptr_t)gmem,
        (__attribute__((address_space(3))) void*)(uint32_t)(uintptr_t)lds,
        16, 0, 0);
}

// ---------------------------------------------------------------- fused cast f32->f16
// Ranges (in float4 units): x 2097152 | w_qkv 786432 (first 262144 scaled by qs) | w_out 262144
__global__ void cast_fused(const float* __restrict__ x, f16* __restrict__ xh,
                           const float* __restrict__ wq, f16* __restrict__ wqh,
                           const float* __restrict__ wo, f16* __restrict__ woh,
                           float qs) {
    int stride = gridDim.x * blockDim.x;
    for (int i = blockIdx.x * blockDim.x + threadIdx.x; i < 3145728; i += stride) {
        const float4* src; f16x4* dst; float s = 1.f;
        if (i < 2097152)      { src = (const float4*)x  + i;            dst = (f16x4*)xh  + i; }
        else if (i < 2883584) { int j = i - 2097152; src = (const float4*)wq + j; dst = (f16x4*)wqh + j;
                                if (j < 262144) s = qs; }
        else                  { int j = i - 2883584; src = (const float4*)wo + j; dst = (f16x4*)woh + j; }
        float4 v = *src;
        f16x4 h = { (f16)(v.x * s), (f16)(v.y * s), (f16)(v.z * s), (f16)(v.w * s) };
        *dst = h;
    }
}

// ---------------------------------------------------------------- pipelined MFMA GEMM: C = A * B^T (+bias)
// BM=256, BN=128, 512 threads = 8 waves (4M x 2N), per-wave 64x64 output.
// K pipeline in phases of 32: 4 LDS slots, slot = phase & 3; staging runs 3
// phases ahead (phase g-1's slot recycled for g+3); steady-state wait is
// vmcnt(6), never 0 in-loop. Raw s_barrier bracketed by compiler fences.
//
// Layout (both-sides-consistent, fixes R4/R5): LDS destination is LINEAR
// (thread tid writes byte tid*16 within the slot section -> wave base +
// lane*16, the only pattern global_load_lds supports). Swizzle lives on
// the GLOBAL SOURCE: physical chunk q of row holds logical k-chunk
// lc = q ^ ((row>>1)&3). Reads fetch logical chunk hi at physical
// hi ^ ((rlo>>1)&3): 2 lanes/bank spread (free).
template <typename TC, bool HAS_BIAS>
__global__ __launch_bounds__(512, 2) void gemm8p(
    const f16* __restrict__ A, const f16* __restrict__ B,
    TC* __restrict__ C, const float* __restrict__ bias,
    int M, int N, int K)
{
    __shared__ __align__(16) char lds[98304];   // A slots [0,65536), B slots [65536,98304)

    const int tid  = threadIdx.x;
    const int lane = tid & 63;
    const int wave = tid >> 6;
    const int rlo  = lane & 15;
    const int hi   = lane >> 4;
    const int wm   = wave & 3;        // 0..3 -> wr = wm*64
    const int wn   = wave >> 2;       // 0..1 -> wc = wn*64
    const int bm   = blockIdx.y * 256;
    const int bn   = blockIdx.x * 128;

    // ---- staging (per phase, per thread): A rows {rA, rA+128}, B row rA, chunk lc
    const int rA = tid >> 2;                          // 0..127
    const int lc = (tid & 3) ^ ((tid >> 3) & 3);      // logical k-chunk staged
    const f16* pA0 = A + (size_t)(bm + rA) * K + lc * 8;
    const f16* pA1 = A + (size_t)(bm + 128 + rA) * K + lc * 8;
    const f16* pB  = B + (size_t)(bn + rA) * K + lc * 8;
    const uint32_t dst0 = (uint32_t)tid * 16;         // slotA + [0,8192): rows 0..127
    const uint32_t dst1 = 8192u + (uint32_t)tid * 16; // slotA + [8192,16384): rows 128..255
    const uint32_t dstB = (uint32_t)tid * 16;         // slotB + [0,8192)

    // ---- fragment read offsets (slot-relative)
    const int fsw = (rlo >> 1) & 3;
    uint32_t afb[4], bfb[4];
#pragma unroll
    for (int m = 0; m < 4; ++m)
        afb[m] = (uint32_t)(wm * 64 + m * 16 + rlo) * 64 + (uint32_t)((hi ^ fsw) << 4);
#pragma unroll
    for (int n = 0; n < 4; ++n)
        bfb[n] = (uint32_t)(wn * 64 + n * 16 + rlo) * 64 + (uint32_t)((hi ^ fsw) << 4);

    f32x4 acc[4][4] = {};
    const int NP = K >> 5;                    // phases (32 for K=1024)

    // ---- stage one phase (3 cp16/thread = 3 VMEM insts/wave)
    auto stage = [&](int sg) {
        const uint32_t sa = (uint32_t)(sg & 3) << 14;            // A slot base (16KB)
        const uint32_t sb = 65536u + ((uint32_t)(sg & 3) << 13); // B slot base (8KB)
        async_cp16(lds + sa + dst0, pA0);
        async_cp16(lds + sa + dst1, pA1);
        async_cp16(lds + sb + dstB, pB);
        pA0 += 32; pA1 += 32; pB += 32;
    };

    // prologue: phases 0,1,2 in flight (9 VMEM/wave)
    stage(0); stage(1); stage(2);

    for (int g = 0; g < NP; ++g) {
        // own phase-g loads done; keep newer phases in flight (never 0 in-loop)
        if (g + 2 < NP)      asm volatile("s_waitcnt vmcnt(6)" ::: "memory");
        else if (g + 1 < NP) asm volatile("s_waitcnt vmcnt(3)" ::: "memory");
        else                 asm volatile("s_waitcnt vmcnt(0)" ::: "memory");
        __builtin_amdgcn_s_barrier();         // all waves' phase-g loads landed
        asm volatile("" ::: "memory");        // compiler fence around the barrier
        __builtin_amdgcn_sched_barrier(0);

        if (g + 3 < NP) stage(g + 3);         // recycles slot (g-1)&3: reads consumed pre-barrier

        const uint32_t sa = (uint32_t)(g & 3) << 14;
        const uint32_t sb = 65536u + ((uint32_t)(g & 3) << 13);

        f16x8 af[4], bf[4];
#pragma unroll
        for (int m = 0; m < 4; ++m)
            af[m] = *(const f16x8*)(lds + sa + afb[m]);
#pragma unroll
        for (int n = 0; n < 4; ++n)
            bf[n] = *(const f16x8*)(lds + sb + bfb[n]);

        __builtin_amdgcn_s_setprio(1);
#pragma unroll
        for (int m = 0; m < 4; ++m)
#pragma unroll
            for (int n = 0; n < 4; ++n)
                acc[m][n] = __builtin_amdgcn_mfma_f32_16x16x32_f16(af[m], bf[n], acc[m][n], 0, 0, 0);
        __builtin_amdgcn_s_setprio(0);
    }

    // ---- epilogue (same C/D mapping as proven kernel)
#pragma unroll
    for (int n = 0; n < 4; ++n) {
        const int gc = bn + wn * 64 + n * 16 + rlo;
        float bv = 0.f;
        if constexpr (HAS_BIAS) bv = bias[gc];
#pragma unroll
        for (int m = 0; m < 4; ++m) {
            const int gr0 = bm + wm * 64 + m * 16 + (hi << 2);
#pragma unroll
            for (int r = 0; r < 4; ++r) {
                float v = acc[m][n][r] + bv;
                if constexpr (sizeof(TC) == 4) C[(size_t)(gr0 + r) * N + gc] = v;
                else                           C[(size_t)(gr0 + r) * N + gc] = (f16)v;
            }
        }
    }
}

// ---------------------------------------------------------------- V transpose: QKV -> Vt[bh][d][seq]
__global__ __launch_bounds__(256) void transpose_v(const f16* __restrict__ qkv, f16* __restrict__ vt) {
    __shared__ float T[64][65];
    const int bid = blockIdx.x, bh = bid >> 5, st = bid & 31;
    const int b = bh >> 4, h = bh & 15, s0 = st * 64;
    const int tid = threadIdx.x;
    const int rs = tid >> 2, c0 = (tid & 3) * 16;
    const f16* src = &qkv[(size_t)(b * 2048 + s0 + rs) * 3072 + 2048 + h * 64 + c0];
    f16x8 v0 = ((const f16x8*)src)[0], v1 = ((const f16x8*)src)[1];
#pragma unroll
    for (int e = 0; e < 8; ++e) { T[rs][c0 + e] = (float)v0[e]; T[rs][c0 + 8 + e] = (float)v1[e]; }
    __syncthreads();
    const int rd = tid >> 2, k0 = (tid & 3) * 16;
    f16x8 w0, w1;
#pragma unroll
    for (int e = 0; e < 8; ++e) { w0[e] = (f16)T[k0 + e][rd]; w1[e] = (f16)T[k0 + 8 + e][rd]; }
    f16* dst = &vt[(size_t)(bh * 64 + rd) * 2048 + s0 + k0];
    ((f16x8*)dst)[0] = w0; ((f16x8*)dst)[1] = w1;
}

// ---------------------------------------------------------------- MFMA flash attention v6 (+setprio)
DINL int phi_row(int r) {
    return (r & 32) | ((r & 12) << 1) | ((r & 16) >> 2) | (r & 3);
}

__global__ __launch_bounds__(256, 4) void attn_mfma(
    const f16* __restrict__ qkv, const f16* __restrict__ vt, f16* __restrict__ out)
{
    constexpr int TD = 3072;
    constexpr int KSTR = 64 * TD;                  // K global advance per tile (f16 elems)
    __shared__ __align__(16) f16 Ks[2][64 * 64];
    __shared__ __align__(16) f16 Vs[2][64 * 64];   // V^T: row=dim, col=key

    const int tid = threadIdx.x, lane = tid & 63, wave = tid >> 6;
    const int bh = blockIdx.x, b = bh >> 4, h = bh & 15;
    const int q0 = blockIdx.y * 128;
    const size_t base = (size_t)b * 2048 * TD + h * 64;
    const int lo = lane & 15, hi = lane >> 4;

    // Q fragments straight from global (B-operand: row = q, k-chunk = hi*8 + 32*ks)
    f16x8 qf[2][2];
#pragma unroll
    for (int g = 0; g < 2; ++g) {
        const f16* qp = &qkv[base + (size_t)(q0 + wave * 32 + g * 16 + lo) * TD + hi * 8];
        qf[g][0] = *(const f16x8*)qp;
        qf[g][1] = *(const f16x8*)(qp + 32);
    }

    // ---- staging pointers (advance by constant stride per tile)
    const int s1 = tid,        r1 = s1 >> 3, c1 = (s1 & 7) ^ (r1 & 7);
    const int s2 = tid + 256,  r2 = s2 >> 3, c2 = (s2 & 7) ^ (r2 & 7);
    const f16* kg1 = &qkv[base + 1024 + (size_t)phi_row(r1) * TD + c1 * 8];
    const f16* kg2 = &qkv[base + 1024 + (size_t)phi_row(r2) * TD + c2 * 8];
    const f16* vg1 = &vt[(size_t)(bh * 64 + r1) * 2048 + c1 * 8];
    const f16* vg2 = &vt[(size_t)(bh * 64 + r2) * 2048 + c2 * 8];
    f16* kd1 = &Ks[0][s1 * 8]; f16* kd2 = &Ks[0][s2 * 8];
    f16* vd1 = &Vs[0][s1 * 8]; f16* vd2 = &Vs[0][s2 * 8];

    // prologue: stage tile 0 into buffer 0
    async_cp16(kd1, kg1); async_cp16(kd2, kg2);
    async_cp16(vd1, vg1); async_cp16(vd2, vg2);
    kg1 += KSTR; kg2 += KSTR; vg1 += 64; vg2 += 64;

    float lsum[2] = {};
    f32x4 o_[2][4] = {};

    for (int jt = 0; jt < 32; ++jt) {
        const int cur = jt & 1;
        __syncthreads();                      // drains staging -> buf[cur] ready
        if (jt + 1 < 32) {
            const int nb = (cur ^ 1) * 4096;  // f16 offset to alt buffer
            async_cp16(kd1 + nb, kg1); async_cp16(kd2 + nb, kg2);
            async_cp16(vd1 + nb, vg1); async_cp16(vd2 + nb, vg2);
            kg1 += KSTR; kg2 += KSTR; vg1 += 64; vg2 += 64;
        }

        // ---- S^T = K Q^T : sc[g][n] col = q(lo), row = LDS K row (16n + 4hi + r); log2 domain
        f32x4 sc[2][4] = {{}, {}};
        __builtin_amdgcn_s_setprio(1);
#pragma unroll
        for (int ks = 0; ks < 2; ++ks) {
            const int c = ks * 4 + hi;
#pragma unroll
            for (int n = 0; n < 4; ++n) {
                int kr = n * 16 + lo;
                f16x8 kf = *(const f16x8*)&Ks[cur][(kr * 8 + (c ^ (kr & 7))) * 8];
                sc[0][n] = __builtin_amdgcn_mfma_f32_16x16x32_f16(kf, qf[0][ks], sc[0][n], 0, 0, 0);
                sc[1][n] = __builtin_amdgcn_mfma_f32_16x16x32_f16(kf, qf[1][ks], sc[1][n], 0, 0, 0);
            }
        }
        __builtin_amdgcn_s_setprio(0);

        // ---- P = exp2(S^T) packed directly into PV A-fragments (phi makes layouts match)
        f16x8 pa[2][2];
#pragma unroll
        for (int g = 0; g < 2; ++g)
#pragma unroll
        for (int n = 0; n < 4; ++n) {
            float p0 = exp2f(sc[g][n][0]), p1 = exp2f(sc[g][n][1]);
            float p2 = exp2f(sc[g][n][2]), p3 = exp2f(sc[g][n][3]);
            lsum[g] += (p0 + p1) + (p2 + p3);
            const int off = (n & 1) * 4;
            const int w = n >> 1;
            pa[g][w][off]   = (f16)p0; pa[g][w][off+1] = (f16)p1;
            pa[g][w][off+2] = (f16)p2; pa[g][w][off+3] = (f16)p3;
        }

        // ---- O += P V  (A = pa (in regs), B = V^T[dim][key])
        __builtin_amdgcn_s_setprio(1);
#pragma unroll
        for (int ks = 0; ks < 2; ++ks) {
            const int c = ks * 4 + hi;
#pragma unroll
            for (int n = 0; n < 4; ++n) {
                int dd = n * 16 + lo;
                f16x8 vb = *(const f16x8*)&Vs[cur][(dd * 8 + (c ^ (dd & 7))) * 8];
                o_[0][n] = __builtin_amdgcn_mfma_f32_16x16x32_f16(pa[0][ks], vb, o_[0][n], 0, 0, 0);
                o_[1][n] = __builtin_amdgcn_mfma_f32_16x16x32_f16(pa[1][ks], vb, o_[1][n], 0, 0, 0);
            }
        }
        __builtin_amdgcn_s_setprio(0);
    }

    // ---- denominators: sum across the 4 hi-groups, then fetch per output row
#pragma unroll
    for (int g = 0; g < 2; ++g) {
        float ls = lsum[g];
        ls += __shfl_xor(ls, 16);
        ls += __shfl_xor(ls, 32);
#pragma unroll
        for (int r = 0; r < 4; ++r) {
            float inv = 1.f / __shfl(ls, hi * 4 + r);
            int row = q0 + wave * 32 + g * 16 + hi * 4 + r;
#pragma unroll
            for (int n = 0; n < 4; ++n) {
                int dim = h * 64 + n * 16 + lo;
                out[(size_t)(b * 2048 + row) * 1024 + dim] = (f16)(o_[g][n][r] * inv);
            }
        }
    }
}

// ---------------------------------------------------------------- launch
extern "C" void kernel_launch(void* const* d_in, const int* in_sizes, int n_in,
                              void* d_out, int out_size, void* d_ws, size_t ws_size,
                              hipStream_t stream)
{
    int ix = 0, iq = 1, iw = 2, ib = 3;
    for (int i = 0; i < n_in; ++i) {
        if      (in_sizes[i] == 8388608) ix = i;
        else if (in_sizes[i] == 3145728) iq = i;
        else if (in_sizes[i] == 1048576) iw = i;
        else if (in_sizes[i] == 1024)    ib = i;
    }
    const float* x     = (const float*)d_in[ix];
    const float* w_qkv = (const float*)d_in[iq];
    const float* w_out = (const float*)d_in[iw];
    const float* b_out = (const float*)d_in[ib];

    char* ws = (char*)d_ws;
    f16* Xh    = (f16*)(ws + 0);           // 16 MiB (AOh overlays after gemm1)
    f16* AOh   = Xh;
    f16* Wqkvh = (f16*)(ws + 16777216);    //  6 MiB
    f16* QKVh  = (f16*)(ws + 23068672);    // 48 MiB [8192][3072]
    f16* Vth   = (f16*)(ws + 73400320);    // 16 MiB [64][64][2048]
    f16* Wouth = (f16*)(ws + 90177536);    //  2 MiB (end 92,274,688 = r1-proven extent)

    // Fold softmax scale * log2(e) into W_q rows.
    const float QSCALE = 0.03125f * 1.4426950408889634f;

    cast_fused<<<3072, 256, 0, stream>>>(x, Xh, w_qkv, Wqkvh, w_out, Wouth, QSCALE);

    // QKV = X @ Wqkv^T : M=8192, N=3072, K=1024  (24 x 32 = 768 blocks = 3.0 rounds)
    gemm8p<f16, false><<<dim3(24, 32), 512, 0, stream>>>(
        Xh, Wqkvh, QKVh, nullptr, 8192, 3072, 1024);

    transpose_v<<<2048, 256, 0, stream>>>(QKVh, Vth);

    attn_mfma<<<dim3(64, 16), 256, 0, stream>>>(QKVh, Vth, AOh);

    // out = AO @ Wout^T + b : fp32 output (8 x 32 = 256 blocks = exactly 1/CU)
    gemm8p<float, true><<<dim3(8, 32), 512, 0, stream>>>(
        AOh, Wouth, (float*)d_out, b_out, 8192, 1024, 1024);
}